// Round 4
// baseline (304.995 us; speedup 1.0000x reference)
//
#include <hip/hip_runtime.h>
#include <hip/hip_bf16.h>

// minLSTM: pre = x @ W^T + b (M=32768, N=1536, K=512), log-space gates,
// chunked log-space scan over L=4096 per (n,h), out = exp(log_h).
// ALL log-domain values are in LOG2 units (v_exp/v_log are base-2 native).
// Gate math: sigma-sum identity (3 exp + 4 log per position).
// x is NOT pre-converted: fp32 path stages RAW fp32 via global_load_lds
// (async, fire-and-forget, zero staging regs) into a 32KB LDS A-tile with
// 16B-granule XOR swizzle (p = g ^ (row&15), involution; applied on the
// per-lane GLOBAL src addr per m173). fp32->bf16 happens at the LDS->frag
// read via v_cvt_pk_bf16_f32 (2x ds_read_b128 + 4 cvt per fragment).
// bf16 path: round-1 global_load_lds layout verbatim (low 16KB of A region).
// Grid (256, 8): by on x so all 8 col-blocks of a row land on one XCD;
// x (64MB) fits L3 so bx re-reads stay off HBM.

#define H_DIM 512
#define LSEQ 4096
#define NBATCH 8
#define M_TOTAL (NBATCH * LSEQ)  // 32768

#define BM 128
#define BK 64

#define CS 128
#define NC 32            // LSEQ / CS

typedef __attribute__((ext_vector_type(8))) short short8;
typedef __attribute__((ext_vector_type(4))) float floatx4;
typedef __attribute__((ext_vector_type(4))) float float4v;
typedef _Float16 h2 __attribute__((ext_vector_type(2)));
typedef _Float16 h4 __attribute__((ext_vector_type(4)));
typedef __attribute__((ext_vector_type(2))) float float2v;

#define NEG_BIG (-1.0e30f)
#define C_LOG2E 1.4426950408889634f
#define LOG2_HX0 (-19.931568569324174f)   // log2(1e-6)

__device__ __forceinline__ float exp2_hw(float x) {
#if __has_builtin(__builtin_amdgcn_exp2f)
    return __builtin_amdgcn_exp2f(x);     // v_exp_f32
#else
    return exp2f(x);
#endif
}

__device__ __forceinline__ float log2_hw(float x) {
#if __has_builtin(__builtin_amdgcn_logf)
    return __builtin_amdgcn_logf(x);      // v_log_f32 (base-2)
#else
    return log2f(x);
#endif
}

// log2(2^p + 2^q), robust for -inf-ish inputs
__device__ __forceinline__ float logaddexp2_f(float p, float q) {
    float m = fmaxf(p, q);
    float d = -fabsf(p - q);
    return m + log2_hw(1.0f + exp2_hw(d));
}

__device__ __forceinline__ float bf16u_to_f(unsigned short u) {
    unsigned int w = ((unsigned int)u) << 16;
    float f;
    __builtin_memcpy(&f, &w, 4);
    return f;
}

__device__ __forceinline__ unsigned short f_to_bf16u(float f) {
    __hip_bfloat16 h = __float2bfloat16(f);
    unsigned short u;
    __builtin_memcpy(&u, &h, 2);
    return u;
}

// packed f32x2 -> bf16x2 (RNE), single HW instr on gfx950
__device__ __forceinline__ unsigned int cvtpk_bf16(float lo, float hi) {
    unsigned int r;
    asm("v_cvt_pk_bf16_f32 %0, %1, %2" : "=v"(r) : "v"(lo), "v"(hi));
    return r;
}

__device__ __forceinline__ void gload_lds16(const void* g, void* l) {
    __builtin_amdgcn_global_load_lds(
        (const __attribute__((address_space(1))) unsigned int*)g,
        (__attribute__((address_space(3))) unsigned int*)l, 16, 0, 0);
}

// ---------------------------------------------------------------------------
// Kernel 0: dtype detect (single block) + bias -> f32.
// fp32 data: low u16 halves uniform -> bf16-NaN exponent P=1/256,
// E[hits in 16384] = 64; bf16 N(0,1) data: 0 hits.
// ---------------------------------------------------------------------------
__global__ void detect_and_bias(const unsigned short* __restrict__ xu,
                                const void* __restrict__ bsrc,
                                int* __restrict__ flag,
                                float* __restrict__ bdst) {
    __shared__ int cnt;
    if (threadIdx.x == 0) cnt = 0;
    __syncthreads();
    int local = 0;
    for (int i = threadIdx.x; i < 16384; i += 256) {
        unsigned short u = xu[i];
        if (((u >> 7) & 0xFF) == 0xFF) local++;
    }
    if (local) atomicAdd(&cnt, local);
    __syncthreads();
    int f = (cnt > 8) ? 1 : 0;
    if (threadIdx.x == 0) flag[0] = f;
    for (int i = threadIdx.x; i < 3 * H_DIM; i += 256)
        bdst[i] = f ? ((const float*)bsrc)[i]
                    : bf16u_to_f(((const unsigned short*)bsrc)[i]);
}

// ---------------------------------------------------------------------------
// Kernel 0b: normalize W to bf16 (x is never pre-converted).
// W: 1536*512 = 786432 elems = 384 blocks * 256 threads * 8.
// ---------------------------------------------------------------------------
__global__ __launch_bounds__(256)
void convert_w(const void* __restrict__ W, unsigned short* __restrict__ Wc,
               const int* __restrict__ flag) {
    const int i = (blockIdx.x * 256 + threadIdx.x) * 8;
    if (*flag) {
        const float4v* s4 = (const float4v*)((const float*)W + i);
        float4v a = s4[0], b = s4[1];
        short8 v;
        v[0] = (short)f_to_bf16u(a[0]); v[1] = (short)f_to_bf16u(a[1]);
        v[2] = (short)f_to_bf16u(a[2]); v[3] = (short)f_to_bf16u(a[3]);
        v[4] = (short)f_to_bf16u(b[0]); v[5] = (short)f_to_bf16u(b[1]);
        v[6] = (short)f_to_bf16u(b[2]); v[7] = (short)f_to_bf16u(b[3]);
        *(short8*)&Wc[i] = v;
    } else {
        *(short8*)&Wc[i] = *(const short8*)&((const short*)W)[i];
    }
}

// ---------------------------------------------------------------------------
// Kernel 1: GEMM + gate math + fused scan summaries.
// Block 256 = 4 waves (2x2). A staged async from original x:
//   fp32: global_load_lds of raw fp32 into 32KB tile, cvt at frag read.
//   bf16: global_load_lds direct (round-1 layout, low 16KB).
// B staged via global_load_lds from Wc (bf16, 24KB).
// LDS: A 0..32KB | B 32..56KB | sa 56..57KB+1KB | sb; sc overlays A after
// the K-loop. Tail: wave w scans its 32-t sub-segment -> Asub/Bsub; wave 0
// folds 4 -> Asum/Bval.
// ---------------------------------------------------------------------------
__global__ __launch_bounds__(256, 3)
void gemm_gates(const void* __restrict__ x,
                const unsigned short* __restrict__ W,
                const float* __restrict__ bias,
                const int* __restrict__ flag,
                h2* __restrict__ plv,
                float* __restrict__ Asum, float* __restrict__ Bval,
                float* __restrict__ Asub, float* __restrict__ Bsub) {
    __shared__ __align__(16) char ldsbuf[59392];
    float* Af = (float*)ldsbuf;                // 32 KB fp32 A tile (K-loop)
    short* Alds = (short*)ldsbuf;              // 16 KB bf16 A tile (K-loop, bf16 path)
    short* Blds = (short*)(ldsbuf + 32768);    // 24 KB B tile (K-loop)
    h2* sc = (h2*)ldsbuf;                      // 32 KB after K-loop
    float* sa = (float*)(ldsbuf + 57344);      // 1 KB sub-summary A
    float* sb = (float*)(ldsbuf + 58368);      // 1 KB sub-summary B

    const int by = blockIdx.x;             // row block 0..255 (XCD = by%8)
    const int bx = blockIdx.y;             // col block 0..7 (64 cols/gate)
    const int tid = threadIdx.x;
    const int lane = tid & 63;
    const int w = tid >> 6;
    const int wr = (w >> 1) * 64;
    const int wc2 = w & 1;
    const int l8 = lane >> 3, s8 = lane & 7;
    const int sg = s8 ^ l8;                // swizzled global seg (bf16 paths)
    const int r4 = lane >> 4;              // fp32-A: row within 4-row chunk
    const int seg = lane & 15;             // fp32-A: 16B granule within row
    const int fr = lane & 15;
    const int q = lane >> 4;

    const int R0 = by * BM;
    const int f32in = *flag;

    floatx4 acc[4][6];
    #pragma unroll
    for (int i = 0; i < 4; i++)
        #pragma unroll
        for (int j = 0; j < 6; j++)
            acc[i][j] = (floatx4){0.f, 0.f, 0.f, 0.f};

    const float* xf = (const float*)x;
    const short* xh = (const short*)x;
    const short* wg = (const short*)W;

    for (int k0 = 0; k0 < H_DIM; k0 += BK) {
        __syncthreads();
        if (f32in) {
            // Raw fp32 A: 32 chunks of 1KB (4 rows x 256B); wave w stages 8.
            // LDS granule p of row r holds source granule p ^ (r&15):
            // swizzle applied on the per-lane GLOBAL address, LDS linear.
            #pragma unroll
            for (int i = 0; i < 8; i++) {
                int c = w * 8 + i;
                int row = c * 4 + r4;
                int sgf = seg ^ (row & 15);
                const float* g = xf + (size_t)(R0 + row) * H_DIM + k0 + sgf * 4;
                gload_lds16(g, &Af[c * 256]);
            }
        } else {
            #pragma unroll
            for (int i = 0; i < 4; i++) {
                int c = w * 4 + i;
                const short* g = xh + (size_t)(R0 + c * 8 + l8) * H_DIM + k0 + sg * 8;
                gload_lds16(g, &Alds[c * 512]);
            }
        }
        #pragma unroll
        for (int i = 0; i < 6; i++) {
            int c = w * 6 + i;
            int br = c * 8 + l8;
            int wrow = (br >> 6) * H_DIM + bx * 64 + (br & 63);
            const short* g = wg + (size_t)wrow * H_DIM + k0 + sg * 8;
            gload_lds16(g, &Blds[c * 512]);
        }
        __syncthreads();

        #pragma unroll
        for (int ks = 0; ks < 2; ks++) {
            const int s = ks * 4 + q;
            short8 af[4], bf[6];
            if (f32in) {
                // fragment = k s*8..s*8+7 of row ar = fp32 granules
                // g0=2s, g0+1 at LDS positions G1 = g0^(ar&15), G1^1.
                #pragma unroll
                for (int mt = 0; mt < 4; mt++) {
                    int ar = wr + mt * 16 + fr;
                    int G1 = (2 * s) ^ (ar & 15);
                    float4v fa = *(const float4v*)&Af[ar * 64 + G1 * 4];
                    float4v fb = *(const float4v*)&Af[ar * 64 + (G1 ^ 1) * 4];
                    union { short8 v; unsigned int u[4]; } pk;
                    pk.u[0] = cvtpk_bf16(fa[0], fa[1]);
                    pk.u[1] = cvtpk_bf16(fa[2], fa[3]);
                    pk.u[2] = cvtpk_bf16(fb[0], fb[1]);
                    pk.u[3] = cvtpk_bf16(fb[2], fb[3]);
                    af[mt] = pk.v;
                }
            } else {
                #pragma unroll
                for (int mt = 0; mt < 4; mt++) {
                    int ar = wr + mt * 16 + fr;
                    af[mt] = *(const short8*)&Alds[ar * BK + ((s ^ (ar & 7)) << 3)];
                }
            }
            #pragma unroll
            for (int j = 0; j < 6; j++) {
                int nt = (j >> 1) * 4 + wc2 * 2 + (j & 1);
                int brr = nt * 16 + fr;
                bf[j] = *(const short8*)&Blds[brr * BK + ((s ^ (brr & 7)) << 3)];
            }
            #pragma unroll
            for (int mt = 0; mt < 4; mt++)
                #pragma unroll
                for (int j = 0; j < 6; j++)
                    acc[mt][j] = __builtin_amdgcn_mfma_f32_16x16x32_bf16(
                        af[mt], bf[j], acc[mt][j], 0, 0, 0);
        }
    }

    __syncthreads();   // staging LDS dead; reuse as sc

    // Epilogue: C/D layout col=lane&15, row=quad*4+reg [m89/m91].
    // sigma-sum form, all in log2 units:
    //   af=1+2^(-f*log2e), ai=1+2^(-i*log2e), s=af+ai
    //   lf = log2(ai)-log2(s); lv = log2(af)-log2(s) + lg
    //   lg = h>=0 ? log2(h+0.5) : -log2(1+2^(-h*log2e))  (argument-select)
    const int rowb = R0 + wr + q * 4;
    const int tloc0 = wr + q * 4;
    #pragma unroll
    for (int jj = 0; jj < 2; jj++) {
        int hl = wc2 * 32 + jj * 16 + fr;
        int hcol = bx * 64 + hl;
        float bfv = bias[hcol];
        float biv = bias[H_DIM + hcol];
        float bhv = bias[2 * H_DIM + hcol];
        float bf2 = -bfv * C_LOG2E;        // fold bias into exp arg via fma
        float bi2 = -biv * C_LOG2E;
        #pragma unroll
        for (int mt = 0; mt < 4; mt++) {
            #pragma unroll
            for (int r = 0; r < 4; r++) {
                float ef = exp2_hw(fminf(fmaf(acc[mt][jj][r], -C_LOG2E, bf2), 126.0f));
                float ei = exp2_hw(fminf(fmaf(acc[mt][2 + jj][r], -C_LOG2E, bi2), 126.0f));
                float hp = acc[mt][4 + jj][r] + bhv;
                float eh = exp2_hw(fminf(-hp * C_LOG2E, 126.0f));
                float afv = 1.0f + ef, aiv = 1.0f + ei;
                float sfi = afv + aiv;
                float ls = log2_hw(sfi);
                float lf = log2_hw(aiv) - ls;                  // log2 f'
                float marg = (hp >= 0.0f) ? (hp + 0.5f) : (1.0f + eh);
                float lm = log2_hw(marg);
                float lg = (hp >= 0.0f) ? lm : -lm;            // log2 g
                float lv = (log2_hw(afv) - ls) + lg;           // log2 (i' g)
                int row = rowb + mt * 16 + r;
                h2 pk;
                pk[0] = (_Float16)lf;
                pk[1] = (_Float16)lv;
                plv[(size_t)row * H_DIM + hcol] = pk;
                sc[(tloc0 + mt * 16 + r) * 64 + hl] = pk;
            }
        }
    }

    __syncthreads();

    const int n = by >> 5, c = by & 31;
    // Wave w scans t in [w*32, w*32+32) for col=lane; publish sub-summary.
    {
        float a = 0.f, bacc = NEG_BIG;
        const int t0 = w * 32;
        #pragma unroll 4
        for (int t = t0; t < t0 + 32; t++) {
            h2 p = sc[t * 64 + lane];
            float f = (float)p[0];
            bacc = logaddexp2_f(f + bacc, (float)p[1]);
            a += f;
        }
        sa[w * 64 + lane] = a;
        sb[w * 64 + lane] = bacc;
        size_t o = (((size_t)n * NC + c) * 4 + w) * H_DIM + bx * 64 + lane;
        Asub[o] = a;
        Bsub[o] = bacc;
    }
    __syncthreads();

    if (w == 0) {
        float a = sa[lane], b = sb[lane];
        #pragma unroll
        for (int s = 1; s < 4; s++) {
            float as = sa[s * 64 + lane], bs = sb[s * 64 + lane];
            b = logaddexp2_f(as + b, bs);
            a += as;
        }
        size_t o = ((size_t)n * NC + c) * H_DIM + bx * 64 + lane;
        Asum[o] = a;
        Bval[o] = b;
    }
}

// ---------------------------------------------------------------------------
// Kernel 2: sub-chunk replay. Block (cc, n): c = cc>>2, s = cc&3.
// Carry = fold of c chunk summaries + s sub-summaries (<=34 steps), then
// replay 32 timesteps. 2 h-cols/thread, 8B loads. grid (128, 8) = 1024 blocks.
// Carry-fold loads batched 4-wide to hide L2 latency on the runtime loop.
// ---------------------------------------------------------------------------
__global__ __launch_bounds__(256)
void scan_apply(const h2* __restrict__ plv,
                const float* __restrict__ Asum, const float* __restrict__ Bval,
                const float* __restrict__ Asub, const float* __restrict__ Bsub,
                void* __restrict__ outv, const int* __restrict__ flag) {
    const int cc = blockIdx.x;          // 0..127
    const int n = blockIdx.y;
    const int c = cc >> 2, s = cc & 3;
    const int h0 = threadIdx.x * 2;
    const int f32out = *flag;

    float r0 = LOG2_HX0;                // log2(1e-6)
    float r1 = r0;
    size_t so = (size_t)n * NC * H_DIM + h0;
    int cp = 0;
    for (; cp + 4 <= c; cp += 4) {
        float2v A0 = *(const float2v*)&Asum[so + (size_t)(cp + 0) * H_DIM];
        float2v B0 = *(const float2v*)&Bval[so + (size_t)(cp + 0) * H_DIM];
        float2v A1 = *(const float2v*)&Asum[so + (size_t)(cp + 1) * H_DIM];
        float2v B1 = *(const float2v*)&Bval[so + (size_t)(cp + 1) * H_DIM];
        float2v A2 = *(const float2v*)&Asum[so + (size_t)(cp + 2) * H_DIM];
        float2v B2 = *(const float2v*)&Bval[so + (size_t)(cp + 2) * H_DIM];
        float2v A3 = *(const float2v*)&Asum[so + (size_t)(cp + 3) * H_DIM];
        float2v B3 = *(const float2v*)&Bval[so + (size_t)(cp + 3) * H_DIM];
        r0 = logaddexp2_f(A0[0] + r0, B0[0]); r1 = logaddexp2_f(A0[1] + r1, B0[1]);
        r0 = logaddexp2_f(A1[0] + r0, B1[0]); r1 = logaddexp2_f(A1[1] + r1, B1[1]);
        r0 = logaddexp2_f(A2[0] + r0, B2[0]); r1 = logaddexp2_f(A2[1] + r1, B2[1]);
        r0 = logaddexp2_f(A3[0] + r0, B3[0]); r1 = logaddexp2_f(A3[1] + r1, B3[1]);
    }
    for (; cp < c; cp++) {
        float2v A = *(const float2v*)&Asum[so + (size_t)cp * H_DIM];
        float2v B = *(const float2v*)&Bval[so + (size_t)cp * H_DIM];
        r0 = logaddexp2_f(A[0] + r0, B[0]);
        r1 = logaddexp2_f(A[1] + r1, B[1]);
    }
    size_t sub = (((size_t)n * NC + c) * 4) * H_DIM + h0;
    for (int sp = 0; sp < s; sp++) {
        float2v A = *(const float2v*)&Asub[sub + (size_t)sp * H_DIM];
        float2v B = *(const float2v*)&Bsub[sub + (size_t)sp * H_DIM];
        r0 = logaddexp2_f(A[0] + r0, B[0]);
        r1 = logaddexp2_f(A[1] + r1, B[1]);
    }

    size_t base = ((size_t)n * LSEQ + (size_t)c * CS + s * 32) * H_DIM + h0;
    if (f32out) {
        float* of = (float*)outv;
        #pragma unroll 4
        for (int t = 0; t < 32; t++) {
            size_t idx = base + (size_t)t * H_DIM;
            h4 p = *(const h4*)&plv[idx];          // (lf0, lv0, lf1, lv1)
            r0 = logaddexp2_f((float)p[0] + r0, (float)p[1]);
            r1 = logaddexp2_f((float)p[2] + r1, (float)p[3]);
            float2v o2 = {exp2_hw(r0), exp2_hw(r1)};
            *(float2v*)&of[idx] = o2;
        }
    } else {
        unsigned int* ob32 = (unsigned int*)outv;
        #pragma unroll 4
        for (int t = 0; t < 32; t++) {
            size_t idx = base + (size_t)t * H_DIM;
            h4 p = *(const h4*)&plv[idx];
            r0 = logaddexp2_f((float)p[0] + r0, (float)p[1]);
            r1 = logaddexp2_f((float)p[2] + r1, (float)p[3]);
            unsigned int pk = ((unsigned int)f_to_bf16u(exp2_hw(r1)) << 16)
                            | f_to_bf16u(exp2_hw(r0));
            ob32[idx >> 1] = pk;
        }
    }
}

extern "C" void kernel_launch(void* const* d_in, const int* in_sizes, int n_in,
                              void* d_out, int out_size, void* d_ws, size_t ws_size,
                              hipStream_t stream) {
    const void* x = d_in[0];
    const void* W = d_in[1];
    const void* b = d_in[2];

    char* wsb = (char*)d_ws;
    int* flag            = (int*)wsb;                          // 16 B
    float* bconv         = (float*)(wsb + 16);                 // 6 KB
    unsigned short* Wc   = (unsigned short*)(wsb + 16384 + 33554432);  // 1.5 MB
    h2* plv              = (h2*)(wsb + 36700160);              // 64 MB packed (lf,lv)
    float* Asum          = (float*)(wsb + 103809024);          // 512 KB
    float* Bval          = (float*)(wsb + 104333312);          // 512 KB
    float* Asub          = (float*)(wsb + 104857600);          // 2 MB
    float* Bsub          = (float*)(wsb + 106954752);          // 2 MB

    detect_and_bias<<<1, 256, 0, stream>>>((const unsigned short*)x, b, flag, bconv);
    convert_w<<<384, 256, 0, stream>>>(W, Wc, flag);

    dim3 g1(M_TOTAL / BM, H_DIM / 64);   // (256, 8): by on x for XCD share
    gemm_gates<<<g1, 256, 0, stream>>>(x, Wc, bconv, flag, plv, Asum, Bval, Asub, Bsub);

    dim3 g2(NC * 4, NBATCH);             // (128, 8)
    scan_apply<<<g2, 256, 0, stream>>>(plv, Asum, Bval, Asub, Bsub, d_out, flag);
}

// Round 5
// 212.427 us; speedup vs baseline: 1.4358x; 1.4358x over previous
//
#include <hip/hip_runtime.h>
#include <hip/hip_bf16.h>

// minLSTM: pre = x @ W^T + b (M=32768, N=1536, K=512), log-space gates,
// chunked log-space scan over L=4096 per (n,h), out = exp(log_h).
// ALL log-domain values are in LOG2 units (v_exp/v_log are base-2 native).
// Gate math: sigma-sum identity (3 exp + 4 log per position).
// Pipeline: detect(dtype)+bias -> convert x,W to bf16 -> fused GEMM+gates+
// chunk summaries -> sub-chunk replay. GEMM is the round-1 proven shape
// (bf16 global_load_lds staging, 40KB LDS, 3 blocks/CU) with grid (256,8)
// so all 8 col-blocks of a row-block share one XCD L2 (FETCH 133->112MB).
// Rounds 2-4 falsified: any fp32-A-in-GEMM scheme (reg-stage, prefetch,
// raw-fp32 LDS) loses more than the 2-pass convert costs. Do not revisit.

#define H_DIM 512
#define LSEQ 4096
#define NBATCH 8
#define M_TOTAL (NBATCH * LSEQ)  // 32768

#define BM 128
#define BK 64

#define CS 128
#define NC 32            // LSEQ / CS

typedef __attribute__((ext_vector_type(8))) short short8;
typedef __attribute__((ext_vector_type(4))) float floatx4;
typedef __attribute__((ext_vector_type(4))) float float4v;
typedef _Float16 h2 __attribute__((ext_vector_type(2)));
typedef _Float16 h8 __attribute__((ext_vector_type(8)));
typedef __attribute__((ext_vector_type(2))) float float2v;
typedef __attribute__((ext_vector_type(2))) unsigned int uint2v;

#define NEG_BIG (-1.0e30f)
#define C_LOG2E 1.4426950408889634f
#define LOG2_HX0 (-19.931568569324174f)   // log2(1e-6)

__device__ __forceinline__ float exp2_hw(float x) {
#if __has_builtin(__builtin_amdgcn_exp2f)
    return __builtin_amdgcn_exp2f(x);     // v_exp_f32
#else
    return exp2f(x);
#endif
}

__device__ __forceinline__ float log2_hw(float x) {
#if __has_builtin(__builtin_amdgcn_logf)
    return __builtin_amdgcn_logf(x);      // v_log_f32 (base-2)
#else
    return log2f(x);
#endif
}

// log2(2^p + 2^q), robust for -inf-ish inputs
__device__ __forceinline__ float logaddexp2_f(float p, float q) {
    float m = fmaxf(p, q);
    float d = -fabsf(p - q);
    return m + log2_hw(1.0f + exp2_hw(d));
}

__device__ __forceinline__ float bf16u_to_f(unsigned short u) {
    unsigned int w = ((unsigned int)u) << 16;
    float f;
    __builtin_memcpy(&f, &w, 4);
    return f;
}

__device__ __forceinline__ unsigned short f_to_bf16u(float f) {
    __hip_bfloat16 h = __float2bfloat16(f);
    unsigned short u;
    __builtin_memcpy(&u, &h, 2);
    return u;
}

__device__ __forceinline__ void gload_lds16(const void* g, void* l) {
    __builtin_amdgcn_global_load_lds(
        (const __attribute__((address_space(1))) unsigned int*)g,
        (__attribute__((address_space(3))) unsigned int*)l, 16, 0, 0);
}

// ---------------------------------------------------------------------------
// Kernel 0: dtype detect (single block) + bias -> f32.
// fp32 data: low u16 halves uniform -> bf16-NaN exponent P=1/256,
// E[hits in 16384] = 64; bf16 N(0,1) data: 0 hits.
// Vectorized: 8x short8 loads/thread, fully unrolled (8 outstanding loads;
// the old scalar version serialized ~64 HBM latencies = ~25us on 1 block).
// ---------------------------------------------------------------------------
__global__ void detect_and_bias(const unsigned short* __restrict__ xu,
                                const void* __restrict__ bsrc,
                                int* __restrict__ flag,
                                float* __restrict__ bdst) {
    __shared__ int cnt;
    if (threadIdx.x == 0) cnt = 0;
    __syncthreads();
    const short8* x8 = (const short8*)xu;   // 16384 u16 = 2048 short8
    int local = 0;
    #pragma unroll
    for (int j = 0; j < 8; j++) {
        short8 v = x8[threadIdx.x + j * 256];
        #pragma unroll
        for (int e = 0; e < 8; e++) {
            unsigned short u = (unsigned short)v[e];
            if (((u >> 7) & 0xFF) == 0xFF) local++;
        }
    }
    if (local) atomicAdd(&cnt, local);
    __syncthreads();
    int f = (cnt > 8) ? 1 : 0;
    if (threadIdx.x == 0) flag[0] = f;
    #pragma unroll
    for (int j = 0; j < 6; j++) {
        int i = threadIdx.x + j * 256;
        bdst[i] = f ? ((const float*)bsrc)[i]
                    : bf16u_to_f(((const unsigned short*)bsrc)[i]);
    }
}

// ---------------------------------------------------------------------------
// Kernel 0b: normalize x and W to bf16 (role by block range). Vector loads.
//   [0, 8192) -> x (16777216 elems), [8192, 8576) -> W (786432 elems)
// ---------------------------------------------------------------------------
__global__ __launch_bounds__(256)
void convert_inputs(const void* __restrict__ x, const void* __restrict__ W,
                    unsigned short* __restrict__ xc,
                    unsigned short* __restrict__ Wc,
                    const int* __restrict__ flag) {
    const int bx = blockIdx.x;
    const void* src;
    unsigned short* dst;
    int i;
    if (bx < 8192) { src = x; dst = xc; i = (bx * 256 + threadIdx.x) * 8; }
    else           { src = W; dst = Wc; i = ((bx - 8192) * 256 + threadIdx.x) * 8; }
    if (*flag) {
        const float4v* s4 = (const float4v*)((const float*)src + i);
        float4v a = s4[0], b = s4[1];
        short8 v;
        v[0] = (short)f_to_bf16u(a[0]); v[1] = (short)f_to_bf16u(a[1]);
        v[2] = (short)f_to_bf16u(a[2]); v[3] = (short)f_to_bf16u(a[3]);
        v[4] = (short)f_to_bf16u(b[0]); v[5] = (short)f_to_bf16u(b[1]);
        v[6] = (short)f_to_bf16u(b[2]); v[7] = (short)f_to_bf16u(b[3]);
        *(short8*)&dst[i] = v;
    } else {
        *(short8*)&dst[i] = *(const short8*)&((const short*)src)[i];
    }
}

// ---------------------------------------------------------------------------
// Kernel 1: GEMM + gate math + fused scan summaries (round-1 proven shape).
// Block 256 = 4 waves (2x2). global_load_lds width-16 staging, bf16 inputs.
// LDS XOR swizzle (verified: conflicts ~0). Tail: wave w scans its 32-t
// sub-segment -> Asub/Bsub (global) + LDS; wave 0 folds 4 -> Asum/Bval.
// Grid (256, 8): by = blockIdx.x so same-by col-blocks share an XCD L2.
// ---------------------------------------------------------------------------
__global__ __launch_bounds__(256, 3)
void gemm_gates(const unsigned short* __restrict__ x,
                const unsigned short* __restrict__ W,
                const float* __restrict__ bias,
                h2* __restrict__ plv,
                float* __restrict__ Asum, float* __restrict__ Bval,
                float* __restrict__ Asub, float* __restrict__ Bsub) {
    __shared__ __align__(16) char ldsbuf[40960];
    short* Alds = (short*)ldsbuf;              // 16 KB during K-loop
    short* Blds = (short*)(ldsbuf + 16384);    // 24 KB during K-loop
    h2* sc = (h2*)ldsbuf;                      // 32 KB after K-loop
    float* sa = (float*)(ldsbuf + 32768);      // 1 KB sub-summary A
    float* sb = sa + 256;                      // 1 KB sub-summary B

    const int by = blockIdx.x;             // row block 0..255 (XCD = by%8)
    const int bx = blockIdx.y;             // col block 0..7 (64 cols/gate)
    const int tid = threadIdx.x;
    const int lane = tid & 63;
    const int w = tid >> 6;
    const int wr = (w >> 1) * 64;
    const int wc2 = w & 1;
    const int l8 = lane >> 3, s8 = lane & 7;
    const int sg = s8 ^ l8;                // swizzled global seg for staging
    const int fr = lane & 15;
    const int q = lane >> 4;

    const int R0 = by * BM;

    floatx4 acc[4][6];
    #pragma unroll
    for (int i = 0; i < 4; i++)
        #pragma unroll
        for (int j = 0; j < 6; j++)
            acc[i][j] = (floatx4){0.f, 0.f, 0.f, 0.f};

    const short* xg = (const short*)x;
    const short* wg = (const short*)W;

    for (int k0 = 0; k0 < H_DIM; k0 += BK) {
        __syncthreads();
        #pragma unroll
        for (int i = 0; i < 4; i++) {
            int c = w * 4 + i;
            const short* g = xg + (size_t)(R0 + c * 8 + l8) * H_DIM + k0 + sg * 8;
            gload_lds16(g, &Alds[c * 512]);
        }
        #pragma unroll
        for (int i = 0; i < 6; i++) {
            int c = w * 6 + i;
            int br = c * 8 + l8;
            int wrow = (br >> 6) * H_DIM + bx * 64 + (br & 63);
            const short* g = wg + (size_t)wrow * H_DIM + k0 + sg * 8;
            gload_lds16(g, &Blds[c * 512]);
        }
        __syncthreads();

        #pragma unroll
        for (int ks = 0; ks < 2; ks++) {
            const int s = ks * 4 + q;
            short8 af[4], bf[6];
            #pragma unroll
            for (int mt = 0; mt < 4; mt++) {
                int ar = wr + mt * 16 + fr;
                af[mt] = *(const short8*)&Alds[ar * BK + ((s ^ (ar & 7)) << 3)];
            }
            #pragma unroll
            for (int j = 0; j < 6; j++) {
                int nt = (j >> 1) * 4 + wc2 * 2 + (j & 1);
                int brr = nt * 16 + fr;
                bf[j] = *(const short8*)&Blds[brr * BK + ((s ^ (brr & 7)) << 3)];
            }
            #pragma unroll
            for (int mt = 0; mt < 4; mt++)
                #pragma unroll
                for (int j = 0; j < 6; j++)
                    acc[mt][j] = __builtin_amdgcn_mfma_f32_16x16x32_bf16(
                        af[mt], bf[j], acc[mt][j], 0, 0, 0);
        }
    }

    __syncthreads();   // staging LDS dead; reuse as sc

    // Epilogue: C/D layout col=lane&15, row=quad*4+reg [m89/m91].
    // sigma-sum form, all in log2 units:
    //   af=1+2^(-f*log2e), ai=1+2^(-i*log2e), s=af+ai
    //   lf = log2(ai)-log2(s); lv = log2(af)-log2(s) + lg
    //   lg = h>=0 ? log2(h+0.5) : -log2(1+2^(-h*log2e))  (argument-select)
    const int rowb = R0 + wr + q * 4;
    const int tloc0 = wr + q * 4;
    #pragma unroll
    for (int jj = 0; jj < 2; jj++) {
        int hl = wc2 * 32 + jj * 16 + fr;
        int hcol = bx * 64 + hl;
        float bfv = bias[hcol];
        float biv = bias[H_DIM + hcol];
        float bhv = bias[2 * H_DIM + hcol];
        float bf2 = -bfv * C_LOG2E;        // fold bias into exp arg via fma
        float bi2 = -biv * C_LOG2E;
        #pragma unroll
        for (int mt = 0; mt < 4; mt++) {
            #pragma unroll
            for (int r = 0; r < 4; r++) {
                float ef = exp2_hw(fminf(fmaf(acc[mt][jj][r], -C_LOG2E, bf2), 126.0f));
                float ei = exp2_hw(fminf(fmaf(acc[mt][2 + jj][r], -C_LOG2E, bi2), 126.0f));
                float hp = acc[mt][4 + jj][r] + bhv;
                float eh = exp2_hw(fminf(-hp * C_LOG2E, 126.0f));
                float afv = 1.0f + ef, aiv = 1.0f + ei;
                float sfi = afv + aiv;
                float ls = log2_hw(sfi);
                float lf = log2_hw(aiv) - ls;                  // log2 f'
                float marg = (hp >= 0.0f) ? (hp + 0.5f) : (1.0f + eh);
                float lm = log2_hw(marg);
                float lg = (hp >= 0.0f) ? lm : -lm;            // log2 g
                float lv = (log2_hw(afv) - ls) + lg;           // log2 (i' g)
                int row = rowb + mt * 16 + r;
                h2 pk;
                pk[0] = (_Float16)lf;
                pk[1] = (_Float16)lv;
                plv[(size_t)row * H_DIM + hcol] = pk;
                sc[(tloc0 + mt * 16 + r) * 64 + hl] = pk;
            }
        }
    }

    __syncthreads();

    const int n = by >> 5, c = by & 31;
    // Wave w scans t in [w*32, w*32+32) for col=lane; publish sub-summary.
    {
        float a = 0.f, bacc = NEG_BIG;
        const int t0 = w * 32;
        #pragma unroll 4
        for (int t = t0; t < t0 + 32; t++) {
            h2 p = sc[t * 64 + lane];
            float f = (float)p[0];
            bacc = logaddexp2_f(f + bacc, (float)p[1]);
            a += f;
        }
        sa[w * 64 + lane] = a;
        sb[w * 64 + lane] = bacc;
        size_t o = (((size_t)n * NC + c) * 4 + w) * H_DIM + bx * 64 + lane;
        Asub[o] = a;
        Bsub[o] = bacc;
    }
    __syncthreads();

    if (w == 0) {
        float a = sa[lane], b = sb[lane];
        #pragma unroll
        for (int s = 1; s < 4; s++) {
            float as = sa[s * 64 + lane], bs = sb[s * 64 + lane];
            b = logaddexp2_f(as + b, bs);
            a += as;
        }
        size_t o = ((size_t)n * NC + c) * H_DIM + bx * 64 + lane;
        Asum[o] = a;
        Bval[o] = b;
    }
}

// ---------------------------------------------------------------------------
// Kernel 2: sub-chunk replay. Grid (64, 8), 256 threads.
// Block cc: c = cc&31 (low bits -> XCD c%8, SAME XCD whose gemm blocks
// wrote chunk c's plv rows/summaries: gemm linear%8 = by%8 = c%8).
// spair = cc>>5; thread t: s = spair*2 + (t>>7), 4 h-cols = (t&127)*4.
// 4 independent logaddexp2 chains/thread, 16B loads+stores (2x MLP vs the
// old 2-col version). Carry = c chunk folds + s sub folds, then 32-t replay.
// ---------------------------------------------------------------------------
__global__ __launch_bounds__(256)
void scan_apply(const h2* __restrict__ plv,
                const float* __restrict__ Asum, const float* __restrict__ Bval,
                const float* __restrict__ Asub, const float* __restrict__ Bsub,
                void* __restrict__ outv, const int* __restrict__ flag) {
    const int cc = blockIdx.x;          // 0..63
    const int n = blockIdx.y;
    const int c = cc & 31;
    const int s = (cc >> 5) * 2 + (threadIdx.x >> 7);   // wave-uniform
    const int h0 = (threadIdx.x & 127) * 4;
    const int f32out = *flag;

    float r0 = LOG2_HX0, r1 = r0, r2 = r0, r3 = r0;   // log2(1e-6)
    size_t so = (size_t)n * NC * H_DIM + h0;
    int cp = 0;
    for (; cp + 4 <= c; cp += 4) {
        float4v A0 = *(const float4v*)&Asum[so + (size_t)(cp + 0) * H_DIM];
        float4v B0 = *(const float4v*)&Bval[so + (size_t)(cp + 0) * H_DIM];
        float4v A1 = *(const float4v*)&Asum[so + (size_t)(cp + 1) * H_DIM];
        float4v B1 = *(const float4v*)&Bval[so + (size_t)(cp + 1) * H_DIM];
        float4v A2 = *(const float4v*)&Asum[so + (size_t)(cp + 2) * H_DIM];
        float4v B2 = *(const float4v*)&Bval[so + (size_t)(cp + 2) * H_DIM];
        float4v A3 = *(const float4v*)&Asum[so + (size_t)(cp + 3) * H_DIM];
        float4v B3 = *(const float4v*)&Bval[so + (size_t)(cp + 3) * H_DIM];
        r0 = logaddexp2_f(A0[0] + r0, B0[0]); r1 = logaddexp2_f(A0[1] + r1, B0[1]);
        r2 = logaddexp2_f(A0[2] + r2, B0[2]); r3 = logaddexp2_f(A0[3] + r3, B0[3]);
        r0 = logaddexp2_f(A1[0] + r0, B1[0]); r1 = logaddexp2_f(A1[1] + r1, B1[1]);
        r2 = logaddexp2_f(A1[2] + r2, B1[2]); r3 = logaddexp2_f(A1[3] + r3, B1[3]);
        r0 = logaddexp2_f(A2[0] + r0, B2[0]); r1 = logaddexp2_f(A2[1] + r1, B2[1]);
        r2 = logaddexp2_f(A2[2] + r2, B2[2]); r3 = logaddexp2_f(A2[3] + r3, B2[3]);
        r0 = logaddexp2_f(A3[0] + r0, B3[0]); r1 = logaddexp2_f(A3[1] + r1, B3[1]);
        r2 = logaddexp2_f(A3[2] + r2, B3[2]); r3 = logaddexp2_f(A3[3] + r3, B3[3]);
    }
    for (; cp < c; cp++) {
        float4v A = *(const float4v*)&Asum[so + (size_t)cp * H_DIM];
        float4v B = *(const float4v*)&Bval[so + (size_t)cp * H_DIM];
        r0 = logaddexp2_f(A[0] + r0, B[0]); r1 = logaddexp2_f(A[1] + r1, B[1]);
        r2 = logaddexp2_f(A[2] + r2, B[2]); r3 = logaddexp2_f(A[3] + r3, B[3]);
    }
    size_t sub = (((size_t)n * NC + c) * 4) * H_DIM + h0;
    for (int sp = 0; sp < s; sp++) {
        float4v A = *(const float4v*)&Asub[sub + (size_t)sp * H_DIM];
        float4v B = *(const float4v*)&Bsub[sub + (size_t)sp * H_DIM];
        r0 = logaddexp2_f(A[0] + r0, B[0]); r1 = logaddexp2_f(A[1] + r1, B[1]);
        r2 = logaddexp2_f(A[2] + r2, B[2]); r3 = logaddexp2_f(A[3] + r3, B[3]);
    }

    size_t base = ((size_t)n * LSEQ + (size_t)c * CS + s * 32) * H_DIM + h0;
    if (f32out) {
        float* of = (float*)outv;
        #pragma unroll 4
        for (int t = 0; t < 32; t++) {
            size_t idx = base + (size_t)t * H_DIM;
            h8 p = *(const h8*)&plv[idx];     // (lf0,lv0,lf1,lv1,lf2,lv2,lf3,lv3)
            r0 = logaddexp2_f((float)p[0] + r0, (float)p[1]);
            r1 = logaddexp2_f((float)p[2] + r1, (float)p[3]);
            r2 = logaddexp2_f((float)p[4] + r2, (float)p[5]);
            r3 = logaddexp2_f((float)p[6] + r3, (float)p[7]);
            float4v o4 = {exp2_hw(r0), exp2_hw(r1), exp2_hw(r2), exp2_hw(r3)};
            *(float4v*)&of[idx] = o4;
        }
    } else {
        unsigned int* ob32 = (unsigned int*)outv;
        #pragma unroll 4
        for (int t = 0; t < 32; t++) {
            size_t idx = base + (size_t)t * H_DIM;
            h8 p = *(const h8*)&plv[idx];
            r0 = logaddexp2_f((float)p[0] + r0, (float)p[1]);
            r1 = logaddexp2_f((float)p[2] + r1, (float)p[3]);
            r2 = logaddexp2_f((float)p[4] + r2, (float)p[5]);
            r3 = logaddexp2_f((float)p[6] + r3, (float)p[7]);
            uint2v pk;
            pk[0] = ((unsigned int)f_to_bf16u(exp2_hw(r1)) << 16) | f_to_bf16u(exp2_hw(r0));
            pk[1] = ((unsigned int)f_to_bf16u(exp2_hw(r3)) << 16) | f_to_bf16u(exp2_hw(r2));
            *(uint2v*)&ob32[idx >> 1] = pk;
        }
    }
}

extern "C" void kernel_launch(void* const* d_in, const int* in_sizes, int n_in,
                              void* d_out, int out_size, void* d_ws, size_t ws_size,
                              hipStream_t stream) {
    const void* x = d_in[0];
    const void* W = d_in[1];
    const void* b = d_in[2];

    char* wsb = (char*)d_ws;
    int* flag            = (int*)wsb;                          // 16 B
    float* bconv         = (float*)(wsb + 16);                 // 6 KB
    unsigned short* xc   = (unsigned short*)(wsb + 16384);     // 32 MB
    unsigned short* Wc   = (unsigned short*)(wsb + 16384 + 33554432);  // 1.5 MB
    h2* plv              = (h2*)(wsb + 36700160);              // 64 MB packed (lf,lv)
    float* Asum          = (float*)(wsb + 103809024);          // 512 KB
    float* Bval          = (float*)(wsb + 104333312);          // 512 KB
    float* Asub          = (float*)(wsb + 104857600);          // 2 MB
    float* Bsub          = (float*)(wsb + 106954752);          // 2 MB

    detect_and_bias<<<1, 256, 0, stream>>>((const unsigned short*)x, b, flag, bconv);
    convert_inputs<<<8576, 256, 0, stream>>>(x, W, xc, Wc, flag);

    dim3 g1(M_TOTAL / BM, H_DIM / 64);   // (256, 8): by on x for XCD share
    gemm_gates<<<g1, 256, 0, stream>>>(xc, Wc, bconv, plv, Asum, Bval, Asub, Bsub);

    dim3 g2(NC * 2, NBATCH);             // (64, 8): c in low bits for XCD match
    scan_apply<<<g2, 256, 0, stream>>>(plv, Asum, Bval, Asub, Bsub, d_out, flag);
}